// Round 14
// baseline (502.008 us; speedup 1.0000x reference)
//
#include <hip/hip_runtime.h>

#define N_NODES 10000
#define N_EDGES 640000
#define NODE_DIM 64
#define HIDDEN 128
#define NUM_LAYERS 4
#define NT (N_EDGES + N_NODES)   // 650000 edge slots incl. self loops
#define EB8 64                   // edge slots per block in k_edge9

typedef __attribute__((ext_vector_type(8))) short short8v;
typedef __attribute__((ext_vector_type(16))) float f32x16;

// ---------------- init: zero cnt + enc0, detect edge dtype ----------------
__global__ void k_init(const int* __restrict__ ei, int* __restrict__ flag,
                       int* __restrict__ cnt, unsigned int* __restrict__ enc0)
{
    int gid = blockIdx.x * 256 + threadIdx.x;
    if (gid < N_NODES) cnt[gid] = 0;
    for (int i = gid; i < N_NODES * HIDDEN; i += (int)gridDim.x * 256)
        enc0[i] = 0u;
    if (blockIdx.x == 0) {
        __shared__ int nz;
        if (threadIdx.x == 0) nz = 0;
        __syncthreads();
        int found = 0;
        for (int k = threadIdx.x; k < 2048; k += 256) {
            int pos = 2 * (k * 156) + 1;        // odd, < 640000: valid both layouts
            if (ei[pos] != 0) found = 1;
        }
        if (found) atomicOr(&nz, 1);
        __syncthreads();
        if (threadIdx.x == 0) flag[0] = nz;      // 1 = int32 layout, 0 = int64
    }
}

// ---------------- normalize + degree count (fused) ----------------
__global__ void k_norm_count(const int* __restrict__ ei, const int* __restrict__ flag,
                             int* __restrict__ srcN, int* __restrict__ dstN,
                             int* __restrict__ cnt)
{
    int e = blockIdx.x * 256 + threadIdx.x;
    if (e >= N_EDGES) return;
    int s, d;
    if (flag[0]) { s = ei[e];     d = ei[N_EDGES + e]; }
    else         { s = ei[2 * e]; d = ei[2 * (N_EDGES + e)]; }
    srcN[e] = s;
    dstN[e] = d;
    atomicAdd(&cnt[d], 1);
}

// single-block exclusive scan over (cnt[i]+1) -> cursor (self loop included)
__global__ void k_scan(const int* __restrict__ cnt, int* __restrict__ cursor)
{
    __shared__ int part[256];
    const int t = threadIdx.x;
    const int CH = (N_NODES + 255) / 256;        // 40
    int lo = t * CH, hi = min(N_NODES, lo + CH);
    int s = 0;
    for (int i = lo; i < hi; ++i) s += cnt[i] + 1;
    part[t] = s;
    __syncthreads();
    for (int off = 1; off < 256; off <<= 1) {
        int v = (t >= off) ? part[t - off] : 0;
        __syncthreads();
        part[t] += v;
        __syncthreads();
    }
    int base = (t == 0) ? 0 : part[t - 1];
    for (int i = lo; i < hi; ++i) {
        cursor[i] = base;
        base += cnt[i] + 1;
    }
}

// scatter edges + self loops (fused)
__global__ void k_scatter_all(const int* __restrict__ srcN, const int* __restrict__ dstN,
                              int* __restrict__ cursor,
                              int* __restrict__ esrc, int* __restrict__ edst)
{
    int e = blockIdx.x * 256 + threadIdx.x;
    if (e >= NT) return;
    int s, d;
    if (e < N_EDGES) { s = srcN[e]; d = dstN[e]; }
    else             { s = e - N_EDGES; d = s; }
    int pos = atomicAdd(&cursor[d], 1);
    esrc[pos] = s;
    edst[pos] = d;
}

__device__ __forceinline__ unsigned short bf16rne(float f)
{
    unsigned int u = __float_as_uint(f);
    unsigned int r = u + 0x7FFFu + ((u >> 16) & 1u);
    return (unsigned short)(r >> 16);
}

// fragment-linear hi/lo bf16 weight store: Wf[c][tile][p][lane][j]
// (lane = kh*32+m holds W[k=16c+8kh+j][n=32tile+m]); RNE hi + RNE lo.
__device__ __forceinline__ void wfrag_store(short* __restrict__ Wf, int k, int n, float w)
{
    unsigned short hs = bf16rne(w);
    float hf = __uint_as_float((unsigned int)hs << 16);
    unsigned short ls = bf16rne(w - hf);
    int c = k >> 4, kh = (k >> 3) & 1, j = k & 7;
    int tile = n >> 5, m = n & 31;
    int lane = kh * 32 + m;
    size_t base = (size_t)c * 4096 + tile * 1024 + lane * 8 + j;
    Wf[base]       = (short)hs;
    Wf[base + 512] = (short)ls;
}

// unified weight prep: W1 -> Waf (top-bot), Wbf (bot); W2 -> W2f; W_emb; W_fc
__global__ void k_prepall(const float* __restrict__ W1, const float* __restrict__ W2,
                          const float* __restrict__ W_emb, const float* __restrict__ W_fc,
                          short* __restrict__ Waf, short* __restrict__ Wbf,
                          short* __restrict__ W2f, short* __restrict__ Wembf,
                          short* __restrict__ Wfcf)
{
    int i = blockIdx.x * 256 + threadIdx.x;
    if (i < NUM_LAYERS * 16384) {
        int l = i >> 14, rem = i & 16383;        // rem = k*128 + n
        int k = rem >> 7, n = rem & 127;
        float top = W1[l * 32768 + rem];
        float bot = W1[l * 32768 + 16384 + rem];
        wfrag_store(Waf + (size_t)l * 32768, k, n, top - bot);
        wfrag_store(Wbf + (size_t)l * 32768, k, n, bot);
        wfrag_store(W2f + (size_t)l * 32768, k, n, W2[i]);
    } else if (i < NUM_LAYERS * 16384 + 8192) {
        int j = i - NUM_LAYERS * 16384;          // k*128 + n, k<64
        wfrag_store(Wembf, j >> 7, j & 127, W_emb[j]);
    } else if (i < NUM_LAYERS * 16384 + 8192 + 16384) {
        int j = i - NUM_LAYERS * 16384 - 8192;
        wfrag_store(Wfcf, j >> 7, j & 127, W_fc[j]);
    }
}

__device__ __forceinline__ unsigned int encf(float f)
{
    unsigned int b = __float_as_uint(f);
    return b ^ ((unsigned int)((int)b >> 31) | 0x80000000u);
}

__device__ __forceinline__ float decenc(unsigned int u)
{
    unsigned int bits = (u & 0x80000000u) ? (u ^ 0x80000000u) : ~u;
    return __uint_as_float(bits);
}

// relu(a+b) -> bf16 hi (trunc) + lo (trunc), packed pairs (edge hot path).
__device__ __forceinline__ void radd_split4(float4 a, float4 b, uint2& H, uint2& L)
{
    float f0 = fmaxf(a.x + b.x, 0.f), f1 = fmaxf(a.y + b.y, 0.f);
    float f2 = fmaxf(a.z + b.z, 0.f), f3 = fmaxf(a.w + b.w, 0.f);
    unsigned int u0 = __float_as_uint(f0), u1 = __float_as_uint(f1);
    unsigned int u2 = __float_as_uint(f2), u3 = __float_as_uint(f3);
    H.x = (u1 & 0xFFFF0000u) | (u0 >> 16);
    H.y = (u3 & 0xFFFF0000u) | (u2 >> 16);
    float r0 = f0 - __uint_as_float(u0 & 0xFFFF0000u);
    float r1 = f1 - __uint_as_float(u1 & 0xFFFF0000u);
    float r2 = f2 - __uint_as_float(u2 & 0xFFFF0000u);
    float r3 = f3 - __uint_as_float(u3 & 0xFFFF0000u);
    L.x = (__float_as_uint(r0) >> 16) | (__float_as_uint(r1) & 0xFFFF0000u);
    L.y = (__float_as_uint(r2) >> 16) | (__float_as_uint(r3) & 0xFFFF0000u);
}

// plain split: v -> bf16 hi (RNE) + lo (RNE), packed pairs (node GEMM staging).
__device__ __forceinline__ void split4_rne(float4 f, uint2& H, uint2& L)
{
    unsigned int h0 = bf16rne(f.x), h1 = bf16rne(f.y);
    unsigned int h2 = bf16rne(f.z), h3 = bf16rne(f.w);
    H.x = h0 | (h1 << 16);
    H.y = h2 | (h3 << 16);
    float r0 = f.x - __uint_as_float(h0 << 16);
    float r1 = f.y - __uint_as_float(h1 << 16);
    float r2 = f.z - __uint_as_float(h2 << 16);
    float r3 = f.w - __uint_as_float(h3 << 16);
    unsigned int l0 = bf16rne(r0), l1 = bf16rne(r1);
    unsigned int l2 = bf16rne(r2), l3 = bf16rne(r3);
    L.x = l0 | (l1 << 16);
    L.y = l2 | (l3 << 16);
}

// -------- MFMA node GEMM: 64 rows x 128 cols per block, 3-term hi/lo --------
// X = (DEC ? decode(encR)+bprev : Xf); CA = X@WA + biasA; if HASB: CB = X@WB.
// Staging/fragment/D-layout identical to the verified edge kernel. DEC also
// zeroes encZ (ping-pong; each element touched exactly once).
template <int K, bool HASB, bool DEC>
__global__ __launch_bounds__(256) void k_gemmf(
    const float* __restrict__ Xf, const unsigned int* __restrict__ encR,
    unsigned int* __restrict__ encZ, const float* __restrict__ bprev,
    const short* __restrict__ WAf, const short* __restrict__ WBf,
    const float* __restrict__ biasA,
    float* __restrict__ CA, float* __restrict__ CB, int M)
{
    constexpr int CH = K / 16;
    __shared__ __align__(16) short Ts[4 * CH * 64 * 8];
    const int t = threadIdx.x;
    const int row0 = blockIdx.x * 64;

    // ---- stage X hi/lo (4 threads per row; quad = one 64B line per r) ----
    {
        const int row = t >> 2, q = t & 3;
        const int gr = row0 + row;
        const int sfrag = row >> 5, mrow = row & 31;
        const int kh = q >> 1, half = q & 1;
        const int lbase = kh * 32 + mrow;
#pragma unroll
        for (int r = 0; r < CH; ++r) {
            float4 v = make_float4(0.f, 0.f, 0.f, 0.f);
            if (gr < M) {
                const int ko = q * 4 + r * 16;
                if constexpr (DEC) {
                    uint4 u = *(const uint4*)(encR + (size_t)gr * K + ko);
                    v.x = decenc(u.x) + bprev[ko + 0];
                    v.y = decenc(u.y) + bprev[ko + 1];
                    v.z = decenc(u.z) + bprev[ko + 2];
                    v.w = decenc(u.w) + bprev[ko + 3];
                    if (encZ)
                        *(uint4*)(encZ + (size_t)gr * K + ko) = make_uint4(0u, 0u, 0u, 0u);
                } else {
                    v = *(const float4*)(Xf + (size_t)gr * K + ko);
                }
            }
            uint2 H, L;
            split4_rne(v, H, L);
            const int c  = r;
            const int ih = ((0 * 2 + sfrag) * CH + c) * 64 + lbase;   // p=0
            const int il = ((1 * 2 + sfrag) * CH + c) * 64 + lbase;   // p=1
            *(uint2*)(&Ts[(size_t)(ih ^ c) * 8 + half * 4]) = H;
            *(uint2*)(&Ts[(size_t)(il ^ c) * 8 + half * 4]) = L;
        }
    }
    __syncthreads();

    const int lane = t & 63;
    const int wv   = t >> 6;              // wave's 32-col tile
    f32x16 aA0 = {0,0,0,0,0,0,0,0,0,0,0,0,0,0,0,0};
    f32x16 aA1 = {0,0,0,0,0,0,0,0,0,0,0,0,0,0,0,0};
    f32x16 aB0 = {0,0,0,0,0,0,0,0,0,0,0,0,0,0,0,0};
    f32x16 aB1 = {0,0,0,0,0,0,0,0,0,0,0,0,0,0,0,0};

    const short* WpA = WAf + (size_t)wv * 1024 + (size_t)lane * 8;
    const short* WpB = HASB ? (WBf + (size_t)wv * 1024 + (size_t)lane * 8) : nullptr;

#pragma unroll
    for (int c = 0; c < CH; ++c) {
        short8v wah = *(const short8v*)(WpA + (size_t)c * 4096);
        short8v wal = *(const short8v*)(WpA + (size_t)c * 4096 + 512);
        short8v ah0 = *(const short8v*)(&Ts[(size_t)((((0 * 2 + 0) * CH + c) * 64 + lane) ^ c) * 8]);
        short8v ah1 = *(const short8v*)(&Ts[(size_t)((((0 * 2 + 1) * CH + c) * 64 + lane) ^ c) * 8]);
        short8v al0 = *(const short8v*)(&Ts[(size_t)((((1 * 2 + 0) * CH + c) * 64 + lane) ^ c) * 8]);
        short8v al1 = *(const short8v*)(&Ts[(size_t)((((1 * 2 + 1) * CH + c) * 64 + lane) ^ c) * 8]);
        aA0 = __builtin_amdgcn_mfma_f32_32x32x16_bf16(ah0, wah, aA0, 0, 0, 0);
        aA0 = __builtin_amdgcn_mfma_f32_32x32x16_bf16(al0, wah, aA0, 0, 0, 0);
        aA0 = __builtin_amdgcn_mfma_f32_32x32x16_bf16(ah0, wal, aA0, 0, 0, 0);
        aA1 = __builtin_amdgcn_mfma_f32_32x32x16_bf16(ah1, wah, aA1, 0, 0, 0);
        aA1 = __builtin_amdgcn_mfma_f32_32x32x16_bf16(al1, wah, aA1, 0, 0, 0);
        aA1 = __builtin_amdgcn_mfma_f32_32x32x16_bf16(ah1, wal, aA1, 0, 0, 0);
        if constexpr (HASB) {
            short8v wbh = *(const short8v*)(WpB + (size_t)c * 4096);
            short8v wbl = *(const short8v*)(WpB + (size_t)c * 4096 + 512);
            aB0 = __builtin_amdgcn_mfma_f32_32x32x16_bf16(ah0, wbh, aB0, 0, 0, 0);
            aB0 = __builtin_amdgcn_mfma_f32_32x32x16_bf16(al0, wbh, aB0, 0, 0, 0);
            aB0 = __builtin_amdgcn_mfma_f32_32x32x16_bf16(ah0, wbl, aB0, 0, 0, 0);
            aB1 = __builtin_amdgcn_mfma_f32_32x32x16_bf16(ah1, wbh, aB1, 0, 0, 0);
            aB1 = __builtin_amdgcn_mfma_f32_32x32x16_bf16(al1, wbh, aB1, 0, 0, 0);
            aB1 = __builtin_amdgcn_mfma_f32_32x32x16_bf16(ah1, wbl, aB1, 0, 0, 0);
        }
    }

    // ---- store (D layout: col=lane&31, row er=(r&3)+8*(r>>2)+4*kh) ----
    const int m   = lane & 31;
    const int kh  = lane >> 5;
    const int col = wv * 32 + m;
    const float bA = biasA[col];
#pragma unroll
    for (int r = 0; r < 16; ++r) {
        const int er = (r & 3) + 8 * (r >> 2) + 4 * kh;
        const int r0 = row0 + er;
        const int r1 = row0 + 32 + er;
        if (r0 < M) CA[(size_t)r0 * 128 + col] = aA0[r] + bA;
        if (r1 < M) CA[(size_t)r1 * 128 + col] = aA1[r] + bA;
        if constexpr (HASB) {
            if (r0 < M) CB[(size_t)r0 * 128 + col] = aB0[r];
            if (r1 < M) CB[(size_t)r1 * 128 + col] = aB1[r];
        }
    }
}

// ---------------- EdgeConv v9 (R9 verbatim — 87.6 us/layer measured) ----------------
__global__ __launch_bounds__(256, 4) void k_edge9(
    const float* __restrict__ A, const float* __restrict__ Bm,
    const int* __restrict__ esrc, const int* __restrict__ edst,
    const short* __restrict__ W2l, unsigned int* __restrict__ enc)
{
    __shared__ __align__(16) short Ts[2048 * 8];   // 32 KB, fragment-linear
    __shared__ int dsts[EB8];

    const int t = threadIdx.x;
    const int lane = t & 63;
    const int wv   = t >> 6;
    const int nwg = (int)gridDim.x;
    const int orig = (int)blockIdx.x;
    const int xcd = orig & 7, idx = orig >> 3;
    const int qq = nwg >> 3, rr = nwg & 7;
    const int bid = (xcd < rr ? xcd * (qq + 1) : rr * (qq + 1) + (xcd - rr) * qq) + idx;
    const int s0 = bid * EB8;

    const short* Wp = W2l + (size_t)wv * 1024 + (size_t)lane * 8;
    short8v bfh[8], bfl[8];
#pragma unroll
    for (int c = 0; c < 8; ++c) {
        bfh[c] = *(const short8v*)(Wp + (size_t)c * 4096);
        bfl[c] = *(const short8v*)(Wp + (size_t)c * 4096 + 512);
    }

    {
        const int row = t >> 2;
        const int q   = t & 3;
        const int slot = s0 + row;
        int dst = -1, src = 0;
        if (slot < NT) { dst = edst[slot]; src = esrc[slot]; }
        if (q == 0) dsts[row] = dst;
        const int sfrag = row >> 5;
        const int mrow  = row & 31;
        const int kh    = q >> 1;
        const int half  = q & 1;
        const int lbase = kh * 32 + mrow;

        if (dst >= 0) {
            const float* Ar = A  + (size_t)dst * HIDDEN + q * 4;
            const float* Br = Bm + (size_t)src * HIDDEN + q * 4;
#pragma unroll
            for (int r = 0; r < 8; ++r) {
                float4 av = *(const float4*)(Ar + r * 16);
                float4 bv = *(const float4*)(Br + r * 16);
                uint2 H, L;
                radd_split4(av, bv, H, L);
                const int c  = r;
                const int ih = ((sfrag)     * 8 + c) * 64 + lbase;   // p=0
                const int il = ((2 + sfrag) * 8 + c) * 64 + lbase;   // p=1
                *(uint2*)(&Ts[(size_t)(ih ^ c) * 8 + half * 4]) = H;
                *(uint2*)(&Ts[(size_t)(il ^ c) * 8 + half * 4]) = L;
            }
        } else {
            uint2 z = make_uint2(0u, 0u);
#pragma unroll
            for (int r = 0; r < 8; ++r) {
                const int c  = r;
                const int ih = ((sfrag)     * 8 + c) * 64 + lbase;
                const int il = ((2 + sfrag) * 8 + c) * 64 + lbase;
                *(uint2*)(&Ts[(size_t)(ih ^ c) * 8 + half * 4]) = z;
                *(uint2*)(&Ts[(size_t)(il ^ c) * 8 + half * 4]) = z;
            }
        }
    }
    __syncthreads();

    f32x16 acc0 = {0,0,0,0,0,0,0,0,0,0,0,0,0,0,0,0};
    f32x16 acc1 = {0,0,0,0,0,0,0,0,0,0,0,0,0,0,0,0};

#pragma unroll
    for (int c = 0; c < 8; ++c) {
        short8v ah0 = *(const short8v*)(&Ts[(size_t)(((0 * 8 + c) * 64 + lane) ^ c) * 8]);
        short8v ah1 = *(const short8v*)(&Ts[(size_t)(((1 * 8 + c) * 64 + lane) ^ c) * 8]);
        short8v al0 = *(const short8v*)(&Ts[(size_t)(((2 * 8 + c) * 64 + lane) ^ c) * 8]);
        short8v al1 = *(const short8v*)(&Ts[(size_t)(((3 * 8 + c) * 64 + lane) ^ c) * 8]);
        acc0 = __builtin_amdgcn_mfma_f32_32x32x16_bf16(ah0, bfh[c], acc0, 0, 0, 0);
        acc0 = __builtin_amdgcn_mfma_f32_32x32x16_bf16(al0, bfh[c], acc0, 0, 0, 0);
        acc0 = __builtin_amdgcn_mfma_f32_32x32x16_bf16(ah0, bfl[c], acc0, 0, 0, 0);
        acc1 = __builtin_amdgcn_mfma_f32_32x32x16_bf16(ah1, bfh[c], acc1, 0, 0, 0);
        acc1 = __builtin_amdgcn_mfma_f32_32x32x16_bf16(al1, bfh[c], acc1, 0, 0, 0);
        acc1 = __builtin_amdgcn_mfma_f32_32x32x16_bf16(ah1, bfl[c], acc1, 0, 0, 0);
    }

    const int m   = lane & 31;
    const int kh  = lane >> 5;
    const int col = wv * 32 + m;
    const int d_first = dsts[0];
    const int d_last  = dsts[EB8 - 1];
    if (d_first == d_last) {
        if (d_first >= 0) {
            float mx = fmaxf(acc0[0], acc1[0]);
#pragma unroll
            for (int r = 1; r < 16; ++r)
                mx = fmaxf(mx, fmaxf(acc0[r], acc1[r]));
            atomicMax(&enc[(size_t)d_first * HIDDEN + col], encf(mx));
        }
    } else {
        {
            float run = -3.4e38f;
            int curd = dsts[4 * kh];
#pragma unroll
            for (int r = 0; r < 16; ++r) {
                const int er = (r & 3) + 8 * (r >> 2) + 4 * kh;
                int d = dsts[er];
                if (d != curd) {
                    if (curd >= 0)
                        atomicMax(&enc[(size_t)curd * HIDDEN + col], encf(run));
                    curd = d;
                    run = -3.4e38f;
                }
                run = fmaxf(run, acc0[r]);
            }
            if (curd >= 0)
                atomicMax(&enc[(size_t)curd * HIDDEN + col], encf(run));
        }
        {
            float run = -3.4e38f;
            int curd = dsts[32 + 4 * kh];
#pragma unroll
            for (int r = 0; r < 16; ++r) {
                const int er = 32 + (r & 3) + 8 * (r >> 2) + 4 * kh;
                int d = dsts[er];
                if (d != curd) {
                    if (curd >= 0)
                        atomicMax(&enc[(size_t)curd * HIDDEN + col], encf(run));
                    curd = d;
                    run = -3.4e38f;
                }
                run = fmaxf(run, acc1[r]);
            }
            if (curd >= 0)
                atomicMax(&enc[(size_t)curd * HIDDEN + col], encf(run));
        }
    }
}

// ---------------- launch ----------------
extern "C" void kernel_launch(void* const* d_in, const int* in_sizes, int n_in,
                              void* d_out, int out_size, void* d_ws, size_t ws_size,
                              hipStream_t stream)
{
    const float* x     = (const float*)d_in[0];
    const int*   ei    = (const int*)d_in[1];
    const float* W_emb = (const float*)d_in[2];
    const float* b_emb = (const float*)d_in[3];
    const float* W1    = (const float*)d_in[4];
    const float* b1    = (const float*)d_in[5];
    const float* W2    = (const float*)d_in[6];
    const float* b2    = (const float*)d_in[7];
    const float* W_fc  = (const float*)d_in[8];
    const float* b_fc  = (const float*)d_in[9];
    float* out = (float*)d_out;

    char* p = (char*)d_ws;
    auto alloc = [&](size_t bytes) {
        char* r = p;
        p += (bytes + 255) & ~(size_t)255;
        return r;
    };
    float* h    = (float*)alloc((size_t)N_NODES * HIDDEN * 4);
    float* Ab   = (float*)alloc((size_t)N_NODES * HIDDEN * 4);
    float* Bb   = (float*)alloc((size_t)N_NODES * HIDDEN * 4);
    unsigned int* enc0 = (unsigned int*)alloc((size_t)N_NODES * HIDDEN * 4);
    unsigned int* enc1 = (unsigned int*)alloc((size_t)N_NODES * HIDDEN * 4);
    short* Waf  = (short*)alloc((size_t)NUM_LAYERS * 32768 * 2);
    short* Wbf  = (short*)alloc((size_t)NUM_LAYERS * 32768 * 2);
    short* W2f  = (short*)alloc((size_t)NUM_LAYERS * 32768 * 2);
    short* Wembf= (short*)alloc((size_t)16384 * 2);
    short* Wfcf = (short*)alloc((size_t)32768 * 2);
    int* cursor = (int*)alloc(N_NODES * 4);
    int* cnt    = (int*)alloc(N_NODES * 4);
    int* esrc   = (int*)alloc((size_t)NT * 4);
    int* edst   = (int*)alloc((size_t)NT * 4);
    int* srcN   = (int*)alloc((size_t)N_EDGES * 4);
    int* dstN   = (int*)alloc((size_t)N_EDGES * 4);
    int* flag   = (int*)alloc(4);

    unsigned int* encs[2] = {enc0, enc1};

    const int EBLK = (N_EDGES + 255) / 256;
    const int GB   = (N_NODES + 63) / 64;         // 157
    const int EG   = (NT + EB8 - 1) / EB8;        // 10157
    const int PREP = (NUM_LAYERS * 16384 + 8192 + 16384 + 255) / 256;

    k_init<<<(N_NODES * HIDDEN + 255) / 256, 256, 0, stream>>>(ei, flag, cnt, enc0);
    k_norm_count<<<EBLK, 256, 0, stream>>>(ei, flag, srcN, dstN, cnt);
    k_scan<<<1, 256, 0, stream>>>(cnt, cursor);
    k_scatter_all<<<(NT + 255) / 256, 256, 0, stream>>>(srcN, dstN, cursor, esrc, edst);
    k_prepall<<<PREP, 256, 0, stream>>>(W1, W2, W_emb, W_fc, Waf, Wbf, W2f, Wembf, Wfcf);

    // embedding: h = x @ W_emb + b_emb (MFMA)
    k_gemmf<NODE_DIM, false, false><<<GB, 256, 0, stream>>>(
        x, nullptr, nullptr, nullptr, Wembf, nullptr, b_emb, h, nullptr, N_NODES);

    for (int l = 0; l < NUM_LAYERS; ++l) {
        if (l == 0) {
            k_gemmf<HIDDEN, true, false><<<GB, 256, 0, stream>>>(
                h, nullptr, nullptr, nullptr, Waf, Wbf, b1, Ab, Bb, N_NODES);
        } else {
            k_gemmf<HIDDEN, true, true><<<GB, 256, 0, stream>>>(
                nullptr, encs[(l - 1) & 1], encs[l & 1], b2 + (l - 1) * 128,
                Waf + (size_t)l * 32768, Wbf + (size_t)l * 32768,
                b1 + l * 128, Ab, Bb, N_NODES);
        }
        k_edge9<<<EG, 256, 0, stream>>>(Ab, Bb, esrc, edst,
                                        W2f + (size_t)l * 32768, encs[l & 1]);
    }
    // final fc decodes enc[(L-1)&1] + b2[3] (MFMA)
    k_gemmf<HIDDEN, false, true><<<GB, 256, 0, stream>>>(
        nullptr, encs[(NUM_LAYERS - 1) & 1], nullptr, b2 + 3 * 128,
        Wfcf, nullptr, b_fc, out, nullptr, N_NODES);
}

// Round 15
// 496.387 us; speedup vs baseline: 1.0113x; 1.0113x over previous
//
#include <hip/hip_runtime.h>

#define N_NODES 10000
#define N_EDGES 640000
#define NODE_DIM 64
#define HIDDEN 128
#define NUM_LAYERS 4
#define NT (N_EDGES + N_NODES)   // 650000 edge slots incl. self loops
#define EB8 64                   // edge slots per block in k_edge11

typedef __attribute__((ext_vector_type(8))) short short8v;
typedef __attribute__((ext_vector_type(16))) float f32x16;

// ---------------- init: zero cnt + enc0, detect edge dtype ----------------
__global__ void k_init(const int* __restrict__ ei, int* __restrict__ flag,
                       int* __restrict__ cnt, unsigned int* __restrict__ enc0)
{
    int gid = blockIdx.x * 256 + threadIdx.x;
    if (gid < N_NODES) cnt[gid] = 0;
    for (int i = gid; i < N_NODES * HIDDEN; i += (int)gridDim.x * 256)
        enc0[i] = 0u;
    if (blockIdx.x == 0) {
        __shared__ int nz;
        if (threadIdx.x == 0) nz = 0;
        __syncthreads();
        int found = 0;
        for (int k = threadIdx.x; k < 2048; k += 256) {
            int pos = 2 * (k * 156) + 1;        // odd, < 640000: valid both layouts
            if (ei[pos] != 0) found = 1;
        }
        if (found) atomicOr(&nz, 1);
        __syncthreads();
        if (threadIdx.x == 0) flag[0] = nz;      // 1 = int32 layout, 0 = int64
    }
}

// ---------------- normalize + degree count (fused) ----------------
__global__ void k_norm_count(const int* __restrict__ ei, const int* __restrict__ flag,
                             int* __restrict__ srcN, int* __restrict__ dstN,
                             int* __restrict__ cnt)
{
    int e = blockIdx.x * 256 + threadIdx.x;
    if (e >= N_EDGES) return;
    int s, d;
    if (flag[0]) { s = ei[e];     d = ei[N_EDGES + e]; }
    else         { s = ei[2 * e]; d = ei[2 * (N_EDGES + e)]; }
    srcN[e] = s;
    dstN[e] = d;
    atomicAdd(&cnt[d], 1);
}

// single-block exclusive scan over (cnt[i]+1) -> cursor (self loop included)
__global__ void k_scan(const int* __restrict__ cnt, int* __restrict__ cursor)
{
    __shared__ int part[256];
    const int t = threadIdx.x;
    const int CH = (N_NODES + 255) / 256;        // 40
    int lo = t * CH, hi = min(N_NODES, lo + CH);
    int s = 0;
    for (int i = lo; i < hi; ++i) s += cnt[i] + 1;
    part[t] = s;
    __syncthreads();
    for (int off = 1; off < 256; off <<= 1) {
        int v = (t >= off) ? part[t - off] : 0;
        __syncthreads();
        part[t] += v;
        __syncthreads();
    }
    int base = (t == 0) ? 0 : part[t - 1];
    for (int i = lo; i < hi; ++i) {
        cursor[i] = base;
        base += cnt[i] + 1;
    }
}

// scatter edges + self loops (fused)
__global__ void k_scatter_all(const int* __restrict__ srcN, const int* __restrict__ dstN,
                              int* __restrict__ cursor,
                              int* __restrict__ esrc, int* __restrict__ edst)
{
    int e = blockIdx.x * 256 + threadIdx.x;
    if (e >= NT) return;
    int s, d;
    if (e < N_EDGES) { s = srcN[e]; d = dstN[e]; }
    else             { s = e - N_EDGES; d = s; }
    int pos = atomicAdd(&cursor[d], 1);
    esrc[pos] = s;
    edst[pos] = d;
}

__device__ __forceinline__ unsigned short bf16rne(float f)
{
    unsigned int u = __float_as_uint(f);
    unsigned int r = u + 0x7FFFu + ((u >> 16) & 1u);
    return (unsigned short)(r >> 16);
}

// fragment-linear hi/lo bf16 weight store: Wf[c][tile][p][lane][j]
__device__ __forceinline__ void wfrag_store(short* __restrict__ Wf, int k, int n, float w)
{
    unsigned short hs = bf16rne(w);
    float hf = __uint_as_float((unsigned int)hs << 16);
    unsigned short ls = bf16rne(w - hf);
    int c = k >> 4, kh = (k >> 3) & 1, j = k & 7;
    int tile = n >> 5, m = n & 31;
    int lane = kh * 32 + m;
    size_t base = (size_t)c * 4096 + tile * 1024 + lane * 8 + j;
    Wf[base]       = (short)hs;
    Wf[base + 512] = (short)ls;
}

// unified weight prep: W1 -> Waf (top-bot), Wbf (bot); W2 -> W2f; W_emb; W_fc
__global__ void k_prepall(const float* __restrict__ W1, const float* __restrict__ W2,
                          const float* __restrict__ W_emb, const float* __restrict__ W_fc,
                          short* __restrict__ Waf, short* __restrict__ Wbf,
                          short* __restrict__ W2f, short* __restrict__ Wembf,
                          short* __restrict__ Wfcf)
{
    int i = blockIdx.x * 256 + threadIdx.x;
    if (i < NUM_LAYERS * 16384) {
        int l = i >> 14, rem = i & 16383;        // rem = k*128 + n
        int k = rem >> 7, n = rem & 127;
        float top = W1[l * 32768 + rem];
        float bot = W1[l * 32768 + 16384 + rem];
        wfrag_store(Waf + (size_t)l * 32768, k, n, top - bot);
        wfrag_store(Wbf + (size_t)l * 32768, k, n, bot);
        wfrag_store(W2f + (size_t)l * 32768, k, n, W2[i]);
    } else if (i < NUM_LAYERS * 16384 + 8192) {
        int j = i - NUM_LAYERS * 16384;          // k*128 + n, k<64
        wfrag_store(Wembf, j >> 7, j & 127, W_emb[j]);
    } else if (i < NUM_LAYERS * 16384 + 8192 + 16384) {
        int j = i - NUM_LAYERS * 16384 - 8192;
        wfrag_store(Wfcf, j >> 7, j & 127, W_fc[j]);
    }
}

__device__ __forceinline__ unsigned int encf(float f)
{
    unsigned int b = __float_as_uint(f);
    return b ^ ((unsigned int)((int)b >> 31) | 0x80000000u);
}

__device__ __forceinline__ float decenc(unsigned int u)
{
    unsigned int bits = (u & 0x80000000u) ? (u ^ 0x80000000u) : ~u;
    return __uint_as_float(bits);
}

// relu(a+b) -> bf16 hi (trunc) + lo (trunc), packed pairs (edge hot path).
__device__ __forceinline__ void radd_split4(float4 a, float4 b, uint2& H, uint2& L)
{
    float f0 = fmaxf(a.x + b.x, 0.f), f1 = fmaxf(a.y + b.y, 0.f);
    float f2 = fmaxf(a.z + b.z, 0.f), f3 = fmaxf(a.w + b.w, 0.f);
    unsigned int u0 = __float_as_uint(f0), u1 = __float_as_uint(f1);
    unsigned int u2 = __float_as_uint(f2), u3 = __float_as_uint(f3);
    H.x = (u1 & 0xFFFF0000u) | (u0 >> 16);
    H.y = (u3 & 0xFFFF0000u) | (u2 >> 16);
    float r0 = f0 - __uint_as_float(u0 & 0xFFFF0000u);
    float r1 = f1 - __uint_as_float(u1 & 0xFFFF0000u);
    float r2 = f2 - __uint_as_float(u2 & 0xFFFF0000u);
    float r3 = f3 - __uint_as_float(u3 & 0xFFFF0000u);
    L.x = (__float_as_uint(r0) >> 16) | (__float_as_uint(r1) & 0xFFFF0000u);
    L.y = (__float_as_uint(r2) >> 16) | (__float_as_uint(r3) & 0xFFFF0000u);
}

// plain split: v -> bf16 hi (RNE) + lo (RNE), packed pairs (node GEMM staging).
__device__ __forceinline__ void split4_rne(float4 f, uint2& H, uint2& L)
{
    unsigned int h0 = bf16rne(f.x), h1 = bf16rne(f.y);
    unsigned int h2 = bf16rne(f.z), h3 = bf16rne(f.w);
    H.x = h0 | (h1 << 16);
    H.y = h2 | (h3 << 16);
    float r0 = f.x - __uint_as_float(h0 << 16);
    float r1 = f.y - __uint_as_float(h1 << 16);
    float r2 = f.z - __uint_as_float(h2 << 16);
    float r3 = f.w - __uint_as_float(h3 << 16);
    unsigned int l0 = bf16rne(r0), l1 = bf16rne(r1);
    unsigned int l2 = bf16rne(r2), l3 = bf16rne(r3);
    L.x = l0 | (l1 << 16);
    L.y = l2 | (l3 << 16);
}

// -------- MFMA node GEMM: 32 rows x 128 cols per block (grid 313) --------
// X = (DEC ? decode(encR)+bprev : Xf); CA = X@WA + biasA; if HASB: CB = X@WB.
// DEC also zeroes encZ (ping-pong; each element touched exactly once).
template <int K, bool HASB, bool DEC>
__global__ __launch_bounds__(256) void k_gemmf(
    const float* __restrict__ Xf, const unsigned int* __restrict__ encR,
    unsigned int* __restrict__ encZ, const float* __restrict__ bprev,
    const short* __restrict__ WAf, const short* __restrict__ WBf,
    const float* __restrict__ biasA,
    float* __restrict__ CA, float* __restrict__ CB, int M)
{
    constexpr int CH = K / 16;
    __shared__ __align__(16) short Ts[2 * CH * 64 * 8];   // 2 planes x CH x (kh,m)
    const int t = threadIdx.x;
    const int row0 = blockIdx.x * 32;

    // ---- stage X hi/lo: thread (row = t>>3, c = t&7) handles 16 k-values ----
    {
        const int row = t >> 3;
        const int c   = t & 7;
        if (c < CH) {
            const int gr = row0 + row;
            float4 a0 = make_float4(0.f,0.f,0.f,0.f), a1 = a0, a2 = a0, a3 = a0;
            if (gr < M) {
                const int ko = c * 16;
                if constexpr (DEC) {
                    uint4 u0 = *(const uint4*)(encR + (size_t)gr * K + ko);
                    uint4 u1 = *(const uint4*)(encR + (size_t)gr * K + ko + 4);
                    uint4 u2 = *(const uint4*)(encR + (size_t)gr * K + ko + 8);
                    uint4 u3 = *(const uint4*)(encR + (size_t)gr * K + ko + 12);
                    a0 = make_float4(decenc(u0.x) + bprev[ko+0],  decenc(u0.y) + bprev[ko+1],
                                     decenc(u0.z) + bprev[ko+2],  decenc(u0.w) + bprev[ko+3]);
                    a1 = make_float4(decenc(u1.x) + bprev[ko+4],  decenc(u1.y) + bprev[ko+5],
                                     decenc(u1.z) + bprev[ko+6],  decenc(u1.w) + bprev[ko+7]);
                    a2 = make_float4(decenc(u2.x) + bprev[ko+8],  decenc(u2.y) + bprev[ko+9],
                                     decenc(u2.z) + bprev[ko+10], decenc(u2.w) + bprev[ko+11]);
                    a3 = make_float4(decenc(u3.x) + bprev[ko+12], decenc(u3.y) + bprev[ko+13],
                                     decenc(u3.z) + bprev[ko+14], decenc(u3.w) + bprev[ko+15]);
                    if (encZ) {
                        uint4 z = make_uint4(0u, 0u, 0u, 0u);
                        *(uint4*)(encZ + (size_t)gr * K + ko)      = z;
                        *(uint4*)(encZ + (size_t)gr * K + ko + 4)  = z;
                        *(uint4*)(encZ + (size_t)gr * K + ko + 8)  = z;
                        *(uint4*)(encZ + (size_t)gr * K + ko + 12) = z;
                    }
                } else {
                    a0 = *(const float4*)(Xf + (size_t)gr * K + ko);
                    a1 = *(const float4*)(Xf + (size_t)gr * K + ko + 4);
                    a2 = *(const float4*)(Xf + (size_t)gr * K + ko + 8);
                    a3 = *(const float4*)(Xf + (size_t)gr * K + ko + 12);
                }
            }
            uint2 Ha, La, Hb, Lb;
            split4_rne(a0, Ha, La); split4_rne(a1, Hb, Lb);
            uint4 H0 = make_uint4(Ha.x, Ha.y, Hb.x, Hb.y);   // kh=0
            uint4 L0 = make_uint4(La.x, La.y, Lb.x, Lb.y);
            split4_rne(a2, Ha, La); split4_rne(a3, Hb, Lb);
            uint4 H1 = make_uint4(Ha.x, Ha.y, Hb.x, Hb.y);   // kh=1
            uint4 L1 = make_uint4(La.x, La.y, Lb.x, Lb.y);
            const int u_h0 = (((0 * CH + c) * 64 +      row) ^ c) * 8;
            const int u_h1 = (((0 * CH + c) * 64 + 32 + row) ^ c) * 8;
            const int u_l0 = (((1 * CH + c) * 64 +      row) ^ c) * 8;
            const int u_l1 = (((1 * CH + c) * 64 + 32 + row) ^ c) * 8;
            *(uint4*)(&Ts[u_h0]) = H0;
            *(uint4*)(&Ts[u_h1]) = H1;
            *(uint4*)(&Ts[u_l0]) = L0;
            *(uint4*)(&Ts[u_l1]) = L1;
        }
    }
    __syncthreads();

    const int lane = t & 63;
    const int wv   = t >> 6;              // wave's 32-col tile
    f32x16 aA = {0,0,0,0,0,0,0,0,0,0,0,0,0,0,0,0};
    f32x16 aB = {0,0,0,0,0,0,0,0,0,0,0,0,0,0,0,0};

    const short* WpA = WAf + (size_t)wv * 1024 + (size_t)lane * 8;
    const short* WpB = HASB ? (WBf + (size_t)wv * 1024 + (size_t)lane * 8) : nullptr;

#pragma unroll
    for (int c = 0; c < CH; ++c) {
        short8v ah = *(const short8v*)(&Ts[(size_t)((((0 * CH + c) * 64 + lane)) ^ c) * 8]);
        short8v al = *(const short8v*)(&Ts[(size_t)((((1 * CH + c) * 64 + lane)) ^ c) * 8]);
        short8v wah = *(const short8v*)(WpA + (size_t)c * 4096);
        short8v wal = *(const short8v*)(WpA + (size_t)c * 4096 + 512);
        aA = __builtin_amdgcn_mfma_f32_32x32x16_bf16(ah, wah, aA, 0, 0, 0);
        aA = __builtin_amdgcn_mfma_f32_32x32x16_bf16(al, wah, aA, 0, 0, 0);
        aA = __builtin_amdgcn_mfma_f32_32x32x16_bf16(ah, wal, aA, 0, 0, 0);
        if constexpr (HASB) {
            short8v wbh = *(const short8v*)(WpB + (size_t)c * 4096);
            short8v wbl = *(const short8v*)(WpB + (size_t)c * 4096 + 512);
            aB = __builtin_amdgcn_mfma_f32_32x32x16_bf16(ah, wbh, aB, 0, 0, 0);
            aB = __builtin_amdgcn_mfma_f32_32x32x16_bf16(al, wbh, aB, 0, 0, 0);
            aB = __builtin_amdgcn_mfma_f32_32x32x16_bf16(ah, wbl, aB, 0, 0, 0);
        }
    }

    // ---- store (D layout: col=lane&31, row er=(r&3)+8*(r>>2)+4*kh) ----
    const int m   = lane & 31;
    const int kh  = lane >> 5;
    const int col = wv * 32 + m;
    const float bA = biasA[col];
#pragma unroll
    for (int r = 0; r < 16; ++r) {
        const int er = (r & 3) + 8 * (r >> 2) + 4 * kh;
        const int r0 = row0 + er;
        if (r0 < M) {
            CA[(size_t)r0 * 128 + col] = aA[r] + bA;
            if constexpr (HASB) CB[(size_t)r0 * 128 + col] = aB[r];
        }
    }
}

// ---------------- EdgeConv v11: R9 + forced B-register residency ----------------
// launch_bounds(256,3) raises the VGPR cap to ~170 so the 16 B-fragment loads
// (64 VGPR) stay live; sched_barrier(0) pins them before staging. k-loop is
// then pure ds_read+MFMA (no in-loop global latency).
__global__ __launch_bounds__(256, 3) void k_edge11(
    const float* __restrict__ A, const float* __restrict__ Bm,
    const int* __restrict__ esrc, const int* __restrict__ edst,
    const short* __restrict__ W2l, unsigned int* __restrict__ enc)
{
    __shared__ __align__(16) short Ts[2048 * 8];   // 32 KB, fragment-linear
    __shared__ int dsts[EB8];

    const int t = threadIdx.x;
    const int lane = t & 63;
    const int wv   = t >> 6;
    const int nwg = (int)gridDim.x;
    const int orig = (int)blockIdx.x;
    const int xcd = orig & 7, idx = orig >> 3;
    const int qq = nwg >> 3, rr = nwg & 7;
    const int bid = (xcd < rr ? xcd * (qq + 1) : rr * (qq + 1) + (xcd - rr) * qq) + idx;
    const int s0 = bid * EB8;

    // ---- issue the wave's full B-fragment set; pin before staging ----
    const short* Wp = W2l + (size_t)wv * 1024 + (size_t)lane * 8;
    short8v bfh[8], bfl[8];
#pragma unroll
    for (int c = 0; c < 8; ++c) {
        bfh[c] = *(const short8v*)(Wp + (size_t)c * 4096);
        bfl[c] = *(const short8v*)(Wp + (size_t)c * 4096 + 512);
    }
    __builtin_amdgcn_sched_barrier(0);   // keep B live in VGPRs across staging

    // ---- stage T hi/lo (4 threads per edge slot; quad = one 64B line per r) ----
    {
        const int row = t >> 2;
        const int q   = t & 3;
        const int slot = s0 + row;
        int dst = -1, src = 0;
        if (slot < NT) { dst = edst[slot]; src = esrc[slot]; }
        if (q == 0) dsts[row] = dst;
        const int sfrag = row >> 5;
        const int mrow  = row & 31;
        const int kh    = q >> 1;
        const int half  = q & 1;
        const int lbase = kh * 32 + mrow;

        if (dst >= 0) {
            const float* Ar = A  + (size_t)dst * HIDDEN + q * 4;
            const float* Br = Bm + (size_t)src * HIDDEN + q * 4;
#pragma unroll
            for (int r = 0; r < 8; ++r) {
                float4 av = *(const float4*)(Ar + r * 16);
                float4 bv = *(const float4*)(Br + r * 16);
                uint2 H, L;
                radd_split4(av, bv, H, L);
                const int c  = r;
                const int ih = ((sfrag)     * 8 + c) * 64 + lbase;   // p=0
                const int il = ((2 + sfrag) * 8 + c) * 64 + lbase;   // p=1
                *(uint2*)(&Ts[(size_t)(ih ^ c) * 8 + half * 4]) = H;
                *(uint2*)(&Ts[(size_t)(il ^ c) * 8 + half * 4]) = L;
            }
        } else {
            uint2 z = make_uint2(0u, 0u);
#pragma unroll
            for (int r = 0; r < 8; ++r) {
                const int c  = r;
                const int ih = ((sfrag)     * 8 + c) * 64 + lbase;
                const int il = ((2 + sfrag) * 8 + c) * 64 + lbase;
                *(uint2*)(&Ts[(size_t)(ih ^ c) * 8 + half * 4]) = z;
                *(uint2*)(&Ts[(size_t)(il ^ c) * 8 + half * 4]) = z;
            }
        }
    }
    __syncthreads();   // the only block barrier

    f32x16 acc0 = {0,0,0,0,0,0,0,0,0,0,0,0,0,0,0,0};
    f32x16 acc1 = {0,0,0,0,0,0,0,0,0,0,0,0,0,0,0,0};

#pragma unroll
    for (int c = 0; c < 8; ++c) {
        short8v ah0 = *(const short8v*)(&Ts[(size_t)(((0 * 8 + c) * 64 + lane) ^ c) * 8]);
        short8v ah1 = *(const short8v*)(&Ts[(size_t)(((1 * 8 + c) * 64 + lane) ^ c) * 8]);
        short8v al0 = *(const short8v*)(&Ts[(size_t)(((2 * 8 + c) * 64 + lane) ^ c) * 8]);
        short8v al1 = *(const short8v*)(&Ts[(size_t)(((3 * 8 + c) * 64 + lane) ^ c) * 8]);
        acc0 = __builtin_amdgcn_mfma_f32_32x32x16_bf16(ah0, bfh[c], acc0, 0, 0, 0);
        acc0 = __builtin_amdgcn_mfma_f32_32x32x16_bf16(al0, bfh[c], acc0, 0, 0, 0);
        acc0 = __builtin_amdgcn_mfma_f32_32x32x16_bf16(ah0, bfl[c], acc0, 0, 0, 0);
        acc1 = __builtin_amdgcn_mfma_f32_32x32x16_bf16(ah1, bfh[c], acc1, 0, 0, 0);
        acc1 = __builtin_amdgcn_mfma_f32_32x32x16_bf16(al1, bfh[c], acc1, 0, 0, 0);
        acc1 = __builtin_amdgcn_mfma_f32_32x32x16_bf16(ah1, bfl[c], acc1, 0, 0, 0);
    }

    const int m   = lane & 31;
    const int kh  = lane >> 5;
    const int col = wv * 32 + m;
    const int d_first = dsts[0];
    const int d_last  = dsts[EB8 - 1];
    if (d_first == d_last) {
        if (d_first >= 0) {
            float mx = fmaxf(acc0[0], acc1[0]);
#pragma unroll
            for (int r = 1; r < 16; ++r)
                mx = fmaxf(mx, fmaxf(acc0[r], acc1[r]));
            atomicMax(&enc[(size_t)d_first * HIDDEN + col], encf(mx));
        }
    } else {
        {
            float run = -3.4e38f;
            int curd = dsts[4 * kh];
#pragma unroll
            for (int r = 0; r < 16; ++r) {
                const int er = (r & 3) + 8 * (r >> 2) + 4 * kh;
                int d = dsts[er];
                if (d != curd) {
                    if (curd >= 0)
                        atomicMax(&enc[(size_t)curd * HIDDEN + col], encf(run));
                    curd = d;
                    run = -3.4e38f;
                }
                run = fmaxf(run, acc0[r]);
            }
            if (curd >= 0)
                atomicMax(&enc[(size_t)curd * HIDDEN + col], encf(run));
        }
        {
            float run = -3.4e38f;
            int curd = dsts[32 + 4 * kh];
#pragma unroll
            for (int r = 0; r < 16; ++r) {
                const int er = 32 + (r & 3) + 8 * (r >> 2) + 4 * kh;
                int d = dsts[er];
                if (d != curd) {
                    if (curd >= 0)
                        atomicMax(&enc[(size_t)curd * HIDDEN + col], encf(run));
                    curd = d;
                    run = -3.4e38f;
                }
                run = fmaxf(run, acc1[r]);
            }
            if (curd >= 0)
                atomicMax(&enc[(size_t)curd * HIDDEN + col], encf(run));
        }
    }
}

// ---------------- launch ----------------
extern "C" void kernel_launch(void* const* d_in, const int* in_sizes, int n_in,
                              void* d_out, int out_size, void* d_ws, size_t ws_size,
                              hipStream_t stream)
{
    const float* x     = (const float*)d_in[0];
    const int*   ei    = (const int*)d_in[1];
    const float* W_emb = (const float*)d_in[2];
    const float* b_emb = (const float*)d_in[3];
    const float* W1    = (const float*)d_in[4];
    const float* b1    = (const float*)d_in[5];
    const float* W2    = (const float*)d_in[6];
    const float* b2    = (const float*)d_in[7];
    const float* W_fc  = (const float*)d_in[8];
    const float* b_fc  = (const float*)d_in[9];
    float* out = (float*)d_out;

    char* p = (char*)d_ws;
    auto alloc = [&](size_t bytes) {
        char* r = p;
        p += (bytes + 255) & ~(size_t)255;
        return r;
    };
    float* h    = (float*)alloc((size_t)N_NODES * HIDDEN * 4);
    float* Ab   = (float*)alloc((size_t)N_NODES * HIDDEN * 4);
    float* Bb   = (float*)alloc((size_t)N_NODES * HIDDEN * 4);
    unsigned int* enc0 = (unsigned int*)alloc((size_t)N_NODES * HIDDEN * 4);
    unsigned int* enc1 = (unsigned int*)alloc((size_t)N_NODES * HIDDEN * 4);
    short* Waf  = (short*)alloc((size_t)NUM_LAYERS * 32768 * 2);
    short* Wbf  = (short*)alloc((size_t)NUM_LAYERS * 32768 * 2);
    short* W2f  = (short*)alloc((size_t)NUM_LAYERS * 32768 * 2);
    short* Wembf= (short*)alloc((size_t)16384 * 2);
    short* Wfcf = (short*)alloc((size_t)32768 * 2);
    int* cursor = (int*)alloc(N_NODES * 4);
    int* cnt    = (int*)alloc(N_NODES * 4);
    int* esrc   = (int*)alloc((size_t)NT * 4);
    int* edst   = (int*)alloc((size_t)NT * 4);
    int* srcN   = (int*)alloc((size_t)N_EDGES * 4);
    int* dstN   = (int*)alloc((size_t)N_EDGES * 4);
    int* flag   = (int*)alloc(4);

    unsigned int* encs[2] = {enc0, enc1};

    const int EBLK = (N_EDGES + 255) / 256;
    const int GB32 = (N_NODES + 31) / 32;         // 313
    const int EG   = (NT + EB8 - 1) / EB8;        // 10157
    const int PREP = (NUM_LAYERS * 16384 + 8192 + 16384 + 255) / 256;

    k_init<<<(N_NODES * HIDDEN + 255) / 256, 256, 0, stream>>>(ei, flag, cnt, enc0);
    k_norm_count<<<EBLK, 256, 0, stream>>>(ei, flag, srcN, dstN, cnt);
    k_scan<<<1, 256, 0, stream>>>(cnt, cursor);
    k_scatter_all<<<(NT + 255) / 256, 256, 0, stream>>>(srcN, dstN, cursor, esrc, edst);
    k_prepall<<<PREP, 256, 0, stream>>>(W1, W2, W_emb, W_fc, Waf, Wbf, W2f, Wembf, Wfcf);

    // embedding: h = x @ W_emb + b_emb (MFMA)
    k_gemmf<NODE_DIM, false, false><<<GB32, 256, 0, stream>>>(
        x, nullptr, nullptr, nullptr, Wembf, nullptr, b_emb, h, nullptr, N_NODES);

    for (int l = 0; l < NUM_LAYERS; ++l) {
        if (l == 0) {
            k_gemmf<HIDDEN, true, false><<<GB32, 256, 0, stream>>>(
                h, nullptr, nullptr, nullptr, Waf, Wbf, b1, Ab, Bb, N_NODES);
        } else {
            k_gemmf<HIDDEN, true, true><<<GB32, 256, 0, stream>>>(
                nullptr, encs[(l - 1) & 1], encs[l & 1], b2 + (l - 1) * 128,
                Waf + (size_t)l * 32768, Wbf + (size_t)l * 32768,
                b1 + l * 128, Ab, Bb, N_NODES);
        }
        k_edge11<<<EG, 256, 0, stream>>>(Ab, Bb, esrc, edst,
                                         W2f + (size_t)l * 32768, encs[l & 1]);
    }
    // final fc decodes enc[(L-1)&1] + b2[3] (MFMA)
    k_gemmf<HIDDEN, false, true><<<GB32, 256, 0, stream>>>(
        nullptr, encs[(NUM_LAYERS - 1) & 1], nullptr, b2 + 3 * 128,
        Wfcf, nullptr, b_fc, out, nullptr, N_NODES);
}